// Round 2
// baseline (395.732 us; speedup 1.0000x reference)
//
#include <hip/hip_runtime.h>

#define NN 50000
#define FIN 128
#define HC 256
#define NH 8
#define NC 32
#define NE 800000

typedef __attribute__((ext_vector_type(8))) short short8;
typedef __attribute__((ext_vector_type(4))) short short4v;
typedef __attribute__((ext_vector_type(4))) float floatx4;

__device__ __forceinline__ float bf2f(unsigned short u) {
    union { unsigned int i; float f; } v; v.i = ((unsigned int)u) << 16; return v.f;
}
__device__ __forceinline__ unsigned short f2bf(float f) {
    union { float f; unsigned int i; } v; v.f = f;
    unsigned int r = v.i + 0x7fffu + ((v.i >> 16) & 1u);
    return (unsigned short)(r >> 16);
}
__device__ __forceinline__ float lrelu(float x) { return x > 0.f ? x : 0.2f * x; }
__device__ __forceinline__ float ldf(const void* p, int f32, long long i) {
    return f32 ? ((const float*)p)[i] : bf2f(((const unsigned short*)p)[i]);
}
__device__ __forceinline__ int lde(const int* ei, int i64, long long i) {
    return i64 ? (int)((const long long*)ei)[i] : ei[i];
}

// ---- dtype detection: flags[0]=floats are fp32, flags[1]=edges are int64 ----
__global__ __launch_bounds__(256) void k_detect(const unsigned int* __restrict__ dpm,
                                                const unsigned int* __restrict__ ei,
                                                int* __restrict__ flags) {
    __shared__ int s_bad, s_nz;
    int t = threadIdx.x;
    if (t == 0) { s_bad = 0; s_nz = 0; }
    __syncthreads();
    unsigned int w = dpm[t];                       // fp32 dp_mask words are exactly 0 or 2.5f
    if (w != 0u && w != 0x40200000u) atomicAdd(&s_bad, 1);
    if (ei[2 * t + 1] != 0u) atomicAdd(&s_nz, 1);  // int64 edges => all odd words zero
    __syncthreads();
    if (t == 0) { flags[0] = (s_bad == 0) ? 1 : 0; flags[1] = (s_nz == 0) ? 1 : 0; }
}

// ---- canonicalize: wt[c*128+k]=bf16(W[k][c]); attc = [att_src(256), att_dst(256), bias(256)] fp32 ----
__global__ __launch_bounds__(256) void k_prep(const void* __restrict__ W, const void* __restrict__ as_,
                                              const void* __restrict__ ad_, const void* __restrict__ bs_,
                                              const int* __restrict__ flags,
                                              unsigned short* __restrict__ wt, float* __restrict__ attc) {
    int f32 = flags[0];
    int idx = blockIdx.x * 256 + threadIdx.x;      // grid 131*256 = 33536 = 32768+768
    if (idx < FIN * HC) {
        int c = idx >> 7, k = idx & 127;
        wt[idx] = f2bf(ldf(W, f32, (long long)k * HC + c));
    } else {
        int j = idx - FIN * HC;
        if (j < 256)      attc[j] = ldf(as_, f32, j);
        else if (j < 512) attc[j] = ldf(ad_, f32, j - 256);
        else if (j < 768) attc[j] = ldf(bs_, f32, j - 512);
    }
}

// ---- GEMM h = x @ W via MFMA 16x16x32 bf16 ----
__global__ __launch_bounds__(256) void k_gemm(const void* __restrict__ x,
                                              const unsigned short* __restrict__ wt,
                                              const int* __restrict__ flags,
                                              unsigned short* __restrict__ h_out) {
    int f32 = flags[0];
    int wave = threadIdx.x >> 6;
    int lane = threadIdx.x & 63;
    int row0 = blockIdx.x * 64 + wave * 16;
    int lrow = lane & 15;     // A row / B col within tile
    int quad = lane >> 4;     // k chunk of 8
    int row = row0 + lrow;

    short8 a[4];
    #pragma unroll
    for (int q = 0; q < 4; q++)
        #pragma unroll
        for (int j = 0; j < 8; j++) a[q][j] = 0;

    if (row < NN) {
        if (f32) {
            const float* xp = (const float*)x + (long long)row * FIN + quad * 8;
            #pragma unroll
            for (int q = 0; q < 4; q++) {
                floatx4 u0 = *(const floatx4*)(xp + q * 32);
                floatx4 u1 = *(const floatx4*)(xp + q * 32 + 4);
                #pragma unroll
                for (int j = 0; j < 4; j++) {
                    a[q][j]     = (short)f2bf(u0[j]);
                    a[q][j + 4] = (short)f2bf(u1[j]);
                }
            }
        } else {
            const unsigned short* xp = (const unsigned short*)x + (long long)row * FIN + quad * 8;
            #pragma unroll
            for (int q = 0; q < 4; q++) a[q] = *(const short8*)(xp + q * 32);
        }
    }

    #pragma unroll 4
    for (int ct = 0; ct < 16; ct++) {
        floatx4 acc = {0.f, 0.f, 0.f, 0.f};
        const unsigned short* wp = wt + (ct * 16 + lrow) * FIN + quad * 8;
        #pragma unroll
        for (int q = 0; q < 4; q++) {
            short8 b = *(const short8*)(wp + q * 32);
            acc = __builtin_amdgcn_mfma_f32_16x16x32_bf16(a[q], b, acc, 0, 0, 0);
        }
        // C/D: col = lane&15, row = quad*4 + reg
        #pragma unroll
        for (int r = 0; r < 4; r++) {
            int orow = row0 + quad * 4 + r;
            if (orow < NN) h_out[(long long)orow * HC + ct * 16 + lrow] = f2bf(acc[r]);
        }
    }
}

// ---- attention scores a_src/a_dst [N,8] fp32 ----
__global__ __launch_bounds__(256) void k_scores(const unsigned short* __restrict__ h,
                                                const float* __restrict__ attc,
                                                float* __restrict__ a_src, float* __restrict__ a_dst) {
    int gid = blockIdx.x * 256 + threadIdx.x;
    if (gid >= NN * NH) return;
    int n = gid >> 3, hd = gid & 7;
    const unsigned short* hp = h + (long long)n * HC + hd * NC;
    const float* sp = attc + hd * NC;
    const float* dp = attc + 256 + hd * NC;
    float ss = 0.f, ds = 0.f;
    #pragma unroll
    for (int j = 0; j < 4; j++) {
        short8 hv = *(const short8*)(hp + j * 8);
        #pragma unroll
        for (int k = 0; k < 8; k++) {
            float hf = bf2f((unsigned short)hv[k]);
            ss += hf * sp[j * 8 + k];
            ds += hf * dp[j * 8 + k];
        }
    }
    a_src[gid] = ss;
    a_dst[gid] = ds;
}

// ---- degree histogram ----
__global__ __launch_bounds__(256) void k_hist(const int* __restrict__ ei, const int* __restrict__ flags,
                                              int* __restrict__ deg) {
    int e = blockIdx.x * 256 + threadIdx.x;
    if (e >= NE) return;
    atomicAdd(&deg[lde(ei, flags[1], e)], 1);
}

// ---- scan: per-block sums ----
__global__ __launch_bounds__(256) void k_blocksum(const int* __restrict__ deg, int* __restrict__ bsum) {
    __shared__ int sd[4];
    int i = blockIdx.x * 256 + threadIdx.x;
    int v = (i < NN) ? deg[i] : 0;
    #pragma unroll
    for (int off = 32; off >= 1; off >>= 1) v += __shfl_down(v, off);
    if ((threadIdx.x & 63) == 0) sd[threadIdx.x >> 6] = v;
    __syncthreads();
    if (threadIdx.x == 0) bsum[blockIdx.x] = sd[0] + sd[1] + sd[2] + sd[3];
}

// ---- scan: exclusive scan of block sums (nb <= 256) ----
__global__ __launch_bounds__(256) void k_scanb(int* __restrict__ bsum, int nb) {
    __shared__ int s[256];
    int t = threadIdx.x;
    int v0 = (t < nb) ? bsum[t] : 0;
    s[t] = v0; __syncthreads();
    for (int off = 1; off < 256; off <<= 1) {
        int a = s[t];
        int b = (t >= off) ? s[t - off] : 0;
        __syncthreads();
        s[t] = a + b;
        __syncthreads();
    }
    if (t < nb) bsum[t] = s[t] - v0;
}

// ---- scan: per-element exclusive ptr ----
__global__ __launch_bounds__(256) void k_scan(const int* __restrict__ deg, const int* __restrict__ bsum,
                                              int* __restrict__ ptr) {
    __shared__ int s[256];
    int t = threadIdx.x;
    int i = blockIdx.x * 256 + t;
    int v0 = (i < NN) ? deg[i] : 0;
    s[t] = v0; __syncthreads();
    for (int off = 1; off < 256; off <<= 1) {
        int a = s[t];
        int b = (t >= off) ? s[t - off] : 0;
        __syncthreads();
        s[t] = a + b;
        __syncthreads();
    }
    if (i < NN) ptr[i] = bsum[blockIdx.x] + s[t] - v0;
}

// ---- CSR fill (ptr doubles as cursor; afterwards ptr[i] = end offset) ----
__global__ __launch_bounds__(256) void k_fill(const int* __restrict__ ei, const int* __restrict__ flags,
                                              int* __restrict__ ptr, int2* __restrict__ csr) {
    int e = blockIdx.x * 256 + threadIdx.x;
    if (e >= NE) return;
    int i64 = flags[1];
    int dst = lde(ei, i64, e);
    int src = lde(ei, i64, (long long)NE + e);
    int pos = atomicAdd(&ptr[dst], 1);
    csr[pos] = make_int2(src, e);
}

// ---- per-destination softmax + aggregation: one wave per node ----
__global__ __launch_bounds__(256) void k_aggr(const int* __restrict__ ptr, const int* __restrict__ deg,
                                              const int2* __restrict__ csr,
                                              const float* __restrict__ a_src, const float* __restrict__ a_dst,
                                              const unsigned short* __restrict__ h,
                                              const void* __restrict__ dp_mask,
                                              const void* __restrict__ dp_mask_self,
                                              const int* __restrict__ flags, const float* __restrict__ attc,
                                              void* __restrict__ out) {
    int node = blockIdx.x * 4 + (threadIdx.x >> 6);
    int lane = threadIdx.x & 63;
    if (node >= NN) return;
    int f32 = flags[0];
    int cnt = deg[node];
    int start = ptr[node] - cnt;   // ptr holds end offsets after k_fill

    // Phase 1/2 mapping: head = lane&7, edge stride group = lane>>3
    int mh = lane & 7;
    int eg = lane >> 3;
    float adst = a_dst[node * NH + mh];
    float aself = lrelu(a_src[node * NH + mh] + adst);

    float m = aself;
    for (int i = eg; i < cnt; i += 8) {
        int src = csr[start + i].x;
        m = fmaxf(m, lrelu(a_src[src * NH + mh] + adst));
    }
    m = fmaxf(m, __shfl_xor(m, 8));
    m = fmaxf(m, __shfl_xor(m, 16));
    m = fmaxf(m, __shfl_xor(m, 32));

    float s = (eg == 0) ? __expf(aself - m) : 0.f;
    for (int i = eg; i < cnt; i += 8) {
        int src = csr[start + i].x;
        s += __expf(lrelu(a_src[src * NH + mh] + adst) - m);
    }
    s += __shfl_xor(s, 8);
    s += __shfl_xor(s, 16);
    s += __shfl_xor(s, 32);

    // Aggregation mapping: lane handles channels [4*lane, 4*lane+4), head = lane>>3
    int hh = lane >> 3;
    float m2 = __shfl(m, hh);
    float s2 = __shfl(s, hh);
    float adst2 = __shfl(adst, hh);
    float aself2 = __shfl(aself, hh);
    float inv = 1.0f / s2;

    float acc0 = 0.f, acc1 = 0.f, acc2 = 0.f, acc3 = 0.f;
    int cb = lane * 4;
    for (int i = 0; i < cnt; i++) {
        int2 se = csr[start + i];
        float a = lrelu(a_src[se.x * NH + hh] + adst2);
        float p = __expf(a - m2) * inv * ldf(dp_mask, f32, (long long)se.y * NH + hh);
        short4v hv = *(const short4v*)(h + (long long)se.x * HC + cb);
        acc0 += p * bf2f((unsigned short)hv[0]);
        acc1 += p * bf2f((unsigned short)hv[1]);
        acc2 += p * bf2f((unsigned short)hv[2]);
        acc3 += p * bf2f((unsigned short)hv[3]);
    }
    { // self-loop
        float p = __expf(aself2 - m2) * inv * ldf(dp_mask_self, f32, (long long)node * NH + hh);
        short4v hv = *(const short4v*)(h + (long long)node * HC + cb);
        acc0 += p * bf2f((unsigned short)hv[0]);
        acc1 += p * bf2f((unsigned short)hv[1]);
        acc2 += p * bf2f((unsigned short)hv[2]);
        acc3 += p * bf2f((unsigned short)hv[3]);
    }
    float b0 = attc[512 + cb + 0], b1 = attc[512 + cb + 1];
    float b2 = attc[512 + cb + 2], b3 = attc[512 + cb + 3];
    if (f32) {
        floatx4 o = {acc0 + b0, acc1 + b1, acc2 + b2, acc3 + b3};
        *(floatx4*)((float*)out + (long long)node * HC + cb) = o;
    } else {
        short4v o;
        o[0] = (short)f2bf(acc0 + b0);
        o[1] = (short)f2bf(acc1 + b1);
        o[2] = (short)f2bf(acc2 + b2);
        o[3] = (short)f2bf(acc3 + b3);
        *(short4v*)((unsigned short*)out + (long long)node * HC + cb) = o;
    }
}

extern "C" void kernel_launch(void* const* d_in, const int* in_sizes, int n_in,
                              void* d_out, int out_size, void* d_ws, size_t ws_size,
                              hipStream_t stream) {
    const void* x       = d_in[0];
    const int*  ei      = (const int*)d_in[1];
    const void* dp_mask = d_in[2];
    const void* dp_self = d_in[3];
    const void* W       = d_in[4];
    const void* att_s   = d_in[5];
    const void* att_d   = d_in[6];
    const void* bias    = d_in[7];

    char* w = (char*)d_ws;
    unsigned short* h     = (unsigned short*)(w + 0);              // 25,600,000
    float*          a_src = (float*)(w + 25600000);                //  1,600,000
    float*          a_dst = (float*)(w + 27200000);                //  1,600,000
    int*            deg   = (int*)(w + 28800000);                  //    200,704
    int*            ptr   = (int*)(w + 29000704);                  //    200,704
    int*            bsum  = (int*)(w + 29201408);                  //      1,024
    unsigned short* wt    = (unsigned short*)(w + 29202432);       //     65,536
    float*          attc  = (float*)(w + 29267968);                //      4,096
    int*            flags = (int*)(w + 29272064);                  //        256
    int2*           csr   = (int2*)(w + 29272320);                 //  6,400,000
                                                                   // end 35,672,320 B

    hipMemsetAsync(deg, 0, NN * sizeof(int), stream);

    k_detect<<<1, 256, 0, stream>>>((const unsigned int*)dp_mask, (const unsigned int*)ei, flags);
    k_prep<<<131, 256, 0, stream>>>(W, att_s, att_d, bias, flags, wt, attc);
    k_gemm<<<(NN + 63) / 64, 256, 0, stream>>>(x, wt, flags, h);
    k_scores<<<(NN * NH + 255) / 256, 256, 0, stream>>>(h, attc, a_src, a_dst);
    k_hist<<<(NE + 255) / 256, 256, 0, stream>>>(ei, flags, deg);
    int nb = (NN + 255) / 256;  // 196
    k_blocksum<<<nb, 256, 0, stream>>>(deg, bsum);
    k_scanb<<<1, 256, 0, stream>>>(bsum, nb);
    k_scan<<<nb, 256, 0, stream>>>(deg, bsum, ptr);
    k_fill<<<(NE + 255) / 256, 256, 0, stream>>>(ei, flags, ptr, csr);
    k_aggr<<<(NN + 3) / 4, 256, 0, stream>>>(ptr, deg, csr, a_src, a_dst, h,
                                             dp_mask, dp_self, flags, attc, d_out);
}